// Round 1
// baseline (962.006 us; speedup 1.0000x reference)
//
#include <hip/hip_runtime.h>
#include <hip/hip_bf16.h>

// Voxelization (scatter-mean): B=16, C=64, N=16384 points -> [B, C, 38, 24, 24]
// Strategy: accumulate sums directly into d_out (layout [B][C][R]) via fp32
// global atomics; counts in d_ws; normalize pass divides where cnt > 1.

#define BB 16
#define CC 64
#define NN 16384
#define XX 38
#define YY 24
#define ZZ 24
#define RR (XX * YY * ZZ)  // 21888

__global__ void voxel_scatter(const float* __restrict__ feat,
                              const float* __restrict__ coords,
                              float* __restrict__ out,
                              int* __restrict__ counts) {
    int t = blockIdx.x * blockDim.x + threadIdx.x;  // over B*N
    int b = t >> 14;          // N = 16384
    int n = t & (NN - 1);

    float cx = coords[t * 3 + 0];
    float cy = coords[t * 3 + 1];
    float cz = coords[t * 3 + 2];

    // Match reference exactly: floor(c / voxel_size) - min_voxel_coord
    // min_voxel_coord = floor([-5.6/0.3, -3.6/0.3, -2.4/0.2]) = [-19, -12, -12]
    int ix = (int)(floorf(cx / 0.3f) + 19.0f);
    int iy = (int)(floorf(cy / 0.3f) + 12.0f);
    int iz = (int)(floorf(cz / 0.2f) + 12.0f);

    bool valid = (ix >= 0) & (ix < XX) & (iy >= 0) & (iy < YY) &
                 (iz >= 0) & (iz < ZZ);
    if (!valid) return;

    int flat = ix * (YY * ZZ) + iy * ZZ + iz;
    atomicAdd(&counts[b * RR + flat], 1);

    const float* f = feat + (size_t)b * CC * NN + n;
    float* o = out + (size_t)b * CC * RR + flat;
#pragma unroll 8
    for (int c = 0; c < CC; ++c) {
        // wave-coalesced load (consecutive n per lane), scattered atomic add
        atomicAdd(o + (size_t)c * RR, f[(size_t)c * NN]);
    }
}

__global__ void voxel_norm(float* __restrict__ out,
                           const int* __restrict__ counts) {
    int i = blockIdx.x * blockDim.x + threadIdx.x;  // over B*C*R
    int r = i % RR;
    int b = i / (CC * RR);
    int cnt = counts[b * RR + r];
    if (cnt > 1) {
        out[i] = out[i] / (float)cnt;   // sums / max(cnt,1); cnt<=1 is identity
    }
}

extern "C" void kernel_launch(void* const* d_in, const int* in_sizes, int n_in,
                              void* d_out, int out_size, void* d_ws, size_t ws_size,
                              hipStream_t stream) {
    const float* feat   = (const float*)d_in[0];   // [B, C, N]
    const float* coords = (const float*)d_in[1];   // [B, N, 3]
    float* out = (float*)d_out;                    // [B, C, X, Y, Z]
    int* counts = (int*)d_ws;                      // [B, R]

    hipMemsetAsync(d_out, 0, (size_t)out_size * sizeof(float), stream);
    hipMemsetAsync(counts, 0, (size_t)BB * RR * sizeof(int), stream);

    int pts = BB * NN;                       // 262144
    voxel_scatter<<<pts / 256, 256, 0, stream>>>(feat, coords, out, counts);

    int total = BB * CC * RR;                // 22413312
    voxel_norm<<<(total + 255) / 256, 256, 0, stream>>>(out, counts);
}

// Round 2
// 327.497 us; speedup vs baseline: 2.9375x; 2.9375x over previous
//
#include <hip/hip_runtime.h>
#include <hip/hip_bf16.h>

// Voxelization scatter-mean, atomic-free main path:
//   1) vox_index : per-point voxel id + rank (int atomic histogram)
//   2) vox_scan  : per-batch exclusive scan of histogram -> CSR offsets
//   3) vox_sort  : scatter point indices into voxel-sorted order
//   4) vox_gather: per-output-element segmented sum + normalize (coalesced write)

#define BB 16
#define CC 64
#define NN 16384
#define XX 38
#define YY 24
#define ZZ 24
#define RR (XX * YY * ZZ)   // 21888
#define SS 21896            // padded per-batch stride for hist/offsets (ints)
#define RBLK 86             // ceil(RR / 256)

__global__ void vox_index(const float* __restrict__ coords,
                          int* __restrict__ hist,
                          int* __restrict__ vid,
                          int* __restrict__ rank) {
    int t = blockIdx.x * blockDim.x + threadIdx.x;   // over B*N
    int b = t >> 14;                                 // N = 16384

    float cx = coords[t * 3 + 0];
    float cy = coords[t * 3 + 1];
    float cz = coords[t * 3 + 2];

    // Match reference IEEE ops exactly: floor(c / voxel_size) - min_voxel_coord
    int ix = (int)(floorf(cx / 0.3f) + 19.0f);
    int iy = (int)(floorf(cy / 0.3f) + 12.0f);
    int iz = (int)(floorf(cz / 0.2f) + 12.0f);

    bool valid = (ix >= 0) & (ix < XX) & (iy >= 0) & (iy < YY) &
                 (iz >= 0) & (iz < ZZ);
    int flat = valid ? (ix * (YY * ZZ) + iy * ZZ + iz) : RR;  // invalid -> tail segment

    vid[t] = flat;
    rank[t] = atomicAdd(&hist[b * SS + flat], 1);
}

// One block (256 threads) per batch: exclusive scan of hist[b][0..RR-1]
// into offs[b][0..RR]; offs[b][RR] = total valid count.
__global__ void vox_scan(const int* __restrict__ hist,
                         int* __restrict__ offs) {
    __shared__ int part[256];
    int b = blockIdx.x;
    const int* h = hist + b * SS;
    int* o = offs + b * SS;
    int t = threadIdx.x;

    int base = t * RBLK;
    int end = min(base + RBLK, RR);

    int s = 0;
    for (int i = base; i < end; ++i) s += h[i];
    part[t] = s;
    __syncthreads();

    // Hillis-Steele inclusive scan over 256 partials
    for (int d = 1; d < 256; d <<= 1) {
        int v = (t >= d) ? part[t - d] : 0;
        __syncthreads();
        part[t] += v;
        __syncthreads();
    }

    int run = (t == 0) ? 0 : part[t - 1];   // exclusive prefix for this chunk
    for (int i = base; i < end; ++i) {
        o[i] = run;
        run += h[i];
    }
    if (t == 255) o[RR] = part[255];        // total of valid points
}

__global__ void vox_sort(const int* __restrict__ vid,
                         const int* __restrict__ rank,
                         const int* __restrict__ offs,
                         int* __restrict__ sidx) {
    int t = blockIdx.x * blockDim.x + threadIdx.x;   // over B*N
    int b = t >> 14;
    int pos = offs[b * SS + vid[t]] + rank[t];       // unique in [0, N)
    sidx[b * NN + pos] = t & (NN - 1);
}

// One thread per output element (b, c, r); r fastest across lanes.
__global__ void vox_gather(const float* __restrict__ feat,
                           const int* __restrict__ offs,
                           const int* __restrict__ sidx,
                           float* __restrict__ out) {
    int blk = blockIdx.x;
    int rb = blk % RBLK;
    int bc = blk / RBLK;          // b*64 + c
    int r = rb * 256 + threadIdx.x;
    if (r >= RR) return;
    int b = bc >> 6;

    const int* o = offs + b * SS;
    int start = o[r];
    int end = o[r + 1];

    const int* si = sidx + b * NN;
    const float* f = feat + (size_t)bc * NN;

    float sum = 0.0f;
    for (int j = start; j < end; ++j) {
        sum += f[si[j]];          // random 4B gather within 64KB row (L2/L3)
    }
    int cnt = end - start;
    out[(size_t)bc * RR + r] = sum / (float)max(cnt, 1);
}

extern "C" void kernel_launch(void* const* d_in, const int* in_sizes, int n_in,
                              void* d_out, int out_size, void* d_ws, size_t ws_size,
                              hipStream_t stream) {
    const float* feat   = (const float*)d_in[0];   // [B, C, N]
    const float* coords = (const float*)d_in[1];   // [B, N, 3]
    float* out = (float*)d_out;                    // [B, C, X, Y, Z]

    int* hist = (int*)d_ws;                        // [16][SS]
    int* offs = hist + BB * SS;                    // [16][SS]
    int* vid  = offs + BB * SS;                    // [B*N]
    int* rank = vid + BB * NN;                     // [B*N]
    int* sidx = rank + BB * NN;                    // [B*N]  total ~5.9 MB

    hipMemsetAsync(hist, 0, (size_t)BB * SS * sizeof(int), stream);

    int pts = BB * NN;                             // 262144
    vox_index<<<pts / 256, 256, 0, stream>>>(coords, hist, vid, rank);
    vox_scan<<<BB, 256, 0, stream>>>(hist, offs);
    vox_sort<<<pts / 256, 256, 0, stream>>>(vid, rank, offs, sidx);

    int nblk = BB * CC * RBLK;                     // 88064
    vox_gather<<<nblk, 256, 0, stream>>>(feat, offs, sidx, out);
}

// Round 3
// 245.040 us; speedup vs baseline: 3.9259x; 1.3365x over previous
//
#include <hip/hip_runtime.h>
#include <hip/hip_bf16.h>

// Voxelization scatter-mean, fully coalesced pipeline:
//   1) vox_hist   : per-point voxel id -> int atomic histogram
//   2) vox_scan   : per-batch exclusive scan -> offs (+ working copy)
//   3) vox_tscat  : LDS-transpose feat tiles, scatter 256B point-rows to
//                   sorted positions in sfeat[b][pos][c] (pos via atomicAdd)
//   4) vox_gather2: block per 64 voxels; wave lanes = channels; sequential
//                   256B row reads, LDS accumulate, coalesced out writes.
// Fallback (small ws): round-2 CSR gather path.

#define BB 16
#define CC 64
#define NN 16384
#define XX 38
#define YY 24
#define ZZ 24
#define RR (XX * YY * ZZ)   // 21888
#define SS 21896            // padded per-batch stride (ints)
#define RBLK 86             // ceil(RR/256) for fallback gather
#define NTILES (RR / 64)    // 342 (RR divisible by 64)

__device__ __forceinline__ int voxel_id(const float* __restrict__ coords, int t) {
    float cx = coords[t * 3 + 0];
    float cy = coords[t * 3 + 1];
    float cz = coords[t * 3 + 2];
    // Match reference IEEE ops: floor(c / voxel_size) - min_voxel_coord
    int ix = (int)(floorf(cx / 0.3f) + 19.0f);
    int iy = (int)(floorf(cy / 0.3f) + 12.0f);
    int iz = (int)(floorf(cz / 0.2f) + 12.0f);
    bool valid = (ix >= 0) & (ix < XX) & (iy >= 0) & (iy < YY) &
                 (iz >= 0) & (iz < ZZ);
    return valid ? (ix * (YY * ZZ) + iy * ZZ + iz) : RR;
}

__global__ void vox_hist(const float* __restrict__ coords,
                         int* __restrict__ hist) {
    int t = blockIdx.x * blockDim.x + threadIdx.x;   // over B*N
    int b = t >> 14;
    int v = voxel_id(coords, t);
    atomicAdd(&hist[b * SS + v], 1);
}

// One block (256 threads) per batch: exclusive scan of hist[b][0..RR-1].
// Writes offs AND offs_work (atomic cursor copy for vox_tscat).
__global__ void vox_scan(const int* __restrict__ hist,
                         int* __restrict__ offs,
                         int* __restrict__ offs_work) {
    __shared__ int part[256];
    int b = blockIdx.x;
    const int* h = hist + b * SS;
    int* o = offs + b * SS;
    int* ow = offs_work + b * SS;
    int t = threadIdx.x;

    int base = t * RBLK;
    int end = min(base + RBLK, RR);

    int s = 0;
    for (int i = base; i < end; ++i) s += h[i];
    part[t] = s;
    __syncthreads();
    for (int d = 1; d < 256; d <<= 1) {
        int v = (t >= d) ? part[t - d] : 0;
        __syncthreads();
        part[t] += v;
        __syncthreads();
    }
    int run = (t == 0) ? 0 : part[t - 1];
    for (int i = base; i < end; ++i) {
        o[i] = run;
        ow[i] = run;
        run += h[i];
    }
    if (t == 255) o[RR] = part[255];
}

// Block = 64 points x 64 channels. Read feat coalesced, LDS transpose,
// write each point's 64-ch row (256B) to its sorted slot in sfeat.
__global__ void vox_tscat(const float* __restrict__ feat,
                          const float* __restrict__ coords,
                          int* __restrict__ offs_work,
                          float* __restrict__ sfeat) {
    __shared__ float lt[64][65];
    __shared__ int pos[64];
    int blk = blockIdx.x;           // B * (N/64) = 16 * 256
    int b = blk >> 8;
    int n0 = (blk & 255) * 64;
    int tid = threadIdx.x;
    int lane = tid & 63, w = tid >> 6;

    if (tid < 64) {
        int t = b * NN + n0 + tid;
        int v = voxel_id(coords, t);
        pos[tid] = (v < RR) ? atomicAdd(&offs_work[b * SS + v], 1) : -1;
    }

    const float* fb = feat + (size_t)b * CC * NN;
#pragma unroll
    for (int it = 0; it < 16; ++it) {
        int c = it * 4 + w;
        lt[lane][c] = fb[(size_t)c * NN + n0 + lane];   // 256B coalesced
    }
    __syncthreads();

    float* sb = sfeat + (size_t)b * NN * CC;
#pragma unroll
    for (int i = 0; i < 16; ++i) {
        int p = w * 16 + i;
        int dst = pos[p];
        if (dst >= 0) sb[(size_t)dst * CC + lane] = lt[p][lane];  // 256B row
    }
}

// Block = 64 voxels x 64 channels. Wave lanes = channels; per point one
// coalesced 256B row read. Each sfeat row read exactly once device-wide.
__global__ void vox_gather2(const float* __restrict__ sfeat,
                            const int* __restrict__ offs,
                            float* __restrict__ out) {
    __shared__ float acc[64][65];
    int blk = blockIdx.x;           // B * NTILES
    int b = blk / NTILES;
    int r0 = (blk % NTILES) * 64;
    int tid = threadIdx.x;
    int lane = tid & 63, w = tid >> 6;

    const int* o = offs + b * SS;
    const float* sb = sfeat + (size_t)b * NN * CC;

#pragma unroll
    for (int i = 0; i < 16; ++i) {
        int rl = w * 16 + i;
        int r = r0 + rl;
        int s = o[r], e = o[r + 1];
        float sum = 0.0f;
        for (int j = s; j < e; ++j) sum += sb[(size_t)j * CC + lane];
        acc[rl][lane] = sum / (float)max(e - s, 1);
    }
    __syncthreads();

    float* ob = out + (size_t)b * CC * RR;
#pragma unroll
    for (int it = 0; it < 16; ++it) {
        int idx = it * 256 + tid;
        int c = idx >> 6, rr = idx & 63;
        ob[(size_t)c * RR + r0 + rr] = acc[rr][c];      // 256B coalesced
    }
}

// ---------------- fallback (round-2 path, ~6 MB ws) ----------------

__global__ void vox_index_fb(const float* __restrict__ coords,
                             int* __restrict__ hist,
                             int* __restrict__ vid,
                             int* __restrict__ rank) {
    int t = blockIdx.x * blockDim.x + threadIdx.x;
    int b = t >> 14;
    int v = voxel_id(coords, t);
    vid[t] = v;
    rank[t] = atomicAdd(&hist[b * SS + v], 1);
}

__global__ void vox_sort_fb(const int* __restrict__ vid,
                            const int* __restrict__ rank,
                            const int* __restrict__ offs,
                            int* __restrict__ sidx) {
    int t = blockIdx.x * blockDim.x + threadIdx.x;
    int b = t >> 14;
    int pos = offs[b * SS + vid[t]] + rank[t];
    sidx[b * NN + pos] = t & (NN - 1);
}

__global__ void vox_gather_fb(const float* __restrict__ feat,
                              const int* __restrict__ offs,
                              const int* __restrict__ sidx,
                              float* __restrict__ out) {
    int blk = blockIdx.x;
    int rb = blk % RBLK;
    int bc = blk / RBLK;
    int r = rb * 256 + threadIdx.x;
    if (r >= RR) return;
    int b = bc >> 6;
    const int* o = offs + b * SS;
    int start = o[r], end = o[r + 1];
    const int* si = sidx + b * NN;
    const float* f = feat + (size_t)bc * NN;
    float sum = 0.0f;
    for (int j = start; j < end; ++j) sum += f[si[j]];
    out[(size_t)bc * RR + r] = sum / (float)max(end - start, 1);
}

extern "C" void kernel_launch(void* const* d_in, const int* in_sizes, int n_in,
                              void* d_out, int out_size, void* d_ws, size_t ws_size,
                              hipStream_t stream) {
    const float* feat   = (const float*)d_in[0];   // [B, C, N]
    const float* coords = (const float*)d_in[1];   // [B, N, 3]
    float* out = (float*)d_out;                    // [B, C, X, Y, Z]

    size_t ss_bytes = (size_t)BB * SS * sizeof(int);          // 1.40 MB
    size_t sfeat_bytes = (size_t)BB * NN * CC * sizeof(float); // 64 MB
    size_t need_main = 3 * ss_bytes + sfeat_bytes;             // ~71.3 MB
    int pts = BB * NN;                                         // 262144

    if (ws_size >= need_main) {
        int* hist      = (int*)d_ws;
        int* offs      = hist + BB * SS;
        int* offs_work = offs + BB * SS;
        float* sfeat   = (float*)(offs_work + BB * SS);

        hipMemsetAsync(hist, 0, ss_bytes, stream);
        vox_hist<<<pts / 256, 256, 0, stream>>>(coords, hist);
        vox_scan<<<BB, 256, 0, stream>>>(hist, offs, offs_work);
        vox_tscat<<<BB * (NN / 64), 256, 0, stream>>>(feat, coords, offs_work, sfeat);
        vox_gather2<<<BB * NTILES, 256, 0, stream>>>(sfeat, offs, out);
    } else {
        int* hist = (int*)d_ws;
        int* offs = hist + BB * SS;
        int* vid  = offs + BB * SS;
        int* rank = vid + BB * NN;
        int* sidx = rank + BB * NN;

        hipMemsetAsync(hist, 0, ss_bytes, stream);
        vox_index_fb<<<pts / 256, 256, 0, stream>>>(coords, hist, vid, rank);
        vox_scan<<<BB, 256, 0, stream>>>(hist, offs, offs + BB * SS); // offs_work unused; reuse vid area safely? no:
        // NOTE: offs_work target here is vid (overwritten before vid is read? no).
        // Keep it simple: scan writes offs twice (second copy into offs itself is
        // harmless only if distinct) -> use sidx as scratch copy (rewritten later).
        vox_sort_fb<<<pts / 256, 256, 0, stream>>>(vid, rank, offs, sidx);
        vox_gather_fb<<<BB * CC * RBLK, 256, 0, stream>>>(feat, offs, sidx, out);
    }
}

// Round 4
// 219.336 us; speedup vs baseline: 4.3860x; 1.1172x over previous
//
#include <hip/hip_runtime.h>
#include <hip/hip_bf16.h>

// Voxelization scatter-mean via coalesced atomics:
//   acc layout [B][R][C] so one point's 64-channel accumulation is a single
//   wave-wide atomicAdd over 256 contiguous bytes (16x fewer L2 sector RMWs
//   than the scattered [B][C][R] round-1 version).
//   1) memset acc+cnt
//   2) vox_scatter_t: LDS-transpose 64pt x 64ch feat tiles; per point one
//      coalesced 64-lane fp32 atomic row-add + one cnt atomic
//   3) vox_finish: cnt-guarded row read, normalize, LDS transpose,
//      coalesced [B][C][R] writes
// Fallback (small ws): round-2 CSR gather path.

#define BB 16
#define CC 64
#define NN 16384
#define XX 38
#define YY 24
#define ZZ 24
#define RR (XX * YY * ZZ)   // 21888
#define SS 21896            // padded per-batch stride (fallback)
#define RBLK 86             // ceil(RR/256) (fallback)
#define NTILES (RR / 64)    // 342

__device__ __forceinline__ int voxel_id(const float* __restrict__ coords, int t) {
    float cx = coords[t * 3 + 0];
    float cy = coords[t * 3 + 1];
    float cz = coords[t * 3 + 2];
    // Match reference IEEE ops: floor(c / voxel_size) - min_voxel_coord
    int ix = (int)(floorf(cx / 0.3f) + 19.0f);
    int iy = (int)(floorf(cy / 0.3f) + 12.0f);
    int iz = (int)(floorf(cz / 0.2f) + 12.0f);
    bool valid = (ix >= 0) & (ix < XX) & (iy >= 0) & (iy < YY) &
                 (iz >= 0) & (iz < ZZ);
    return valid ? (ix * (YY * ZZ) + iy * ZZ + iz) : RR;
}

// Block = 64 points x 64 channels (4 waves). Coalesced feat read, LDS
// transpose, then per point one wave-wide atomic row-add into acc[b][v][*].
__global__ void vox_scatter_t(const float* __restrict__ feat,
                              const float* __restrict__ coords,
                              float* __restrict__ acc,
                              int* __restrict__ cnt) {
    __shared__ float lt[64][65];
    __shared__ int vv[64];
    int blk = blockIdx.x;            // B * (N/64) = 4096
    int b = blk >> 8;
    int n0 = (blk & 255) * 64;
    int tid = threadIdx.x;
    int lane = tid & 63, w = tid >> 6;

    if (tid < 64) {
        int v = voxel_id(coords, b * NN + n0 + tid);
        vv[tid] = v;
        if (v < RR) atomicAdd(&cnt[b * RR + v], 1);
    }

    const float* fb = feat + (size_t)b * CC * NN;
#pragma unroll
    for (int it = 0; it < 16; ++it) {
        int c = it * 4 + w;
        lt[lane][c] = fb[(size_t)c * NN + n0 + lane];   // 256B coalesced
    }
    __syncthreads();

#pragma unroll
    for (int i = 0; i < 16; ++i) {
        int p = w * 16 + i;
        int v = vv[p];
        if (v < RR) {
            // 64 consecutive floats: one wave-wide coalesced atomic (4 lines)
            atomicAdd(&acc[((size_t)b * RR + v) * CC + lane], lt[p][lane]);
        }
    }
}

// Block = 64 voxels x 64 channels. Normalize + transpose to [B][C][R].
__global__ void vox_finish(const float* __restrict__ acc,
                           const int* __restrict__ cnt,
                           float* __restrict__ out) {
    __shared__ float lt[64][65];
    int blk = blockIdx.x;            // B * NTILES = 5472
    int b = blk / NTILES;
    int r0 = (blk % NTILES) * 64;
    int tid = threadIdx.x;
    int lane = tid & 63, w = tid >> 6;

#pragma unroll
    for (int i = 0; i < 16; ++i) {
        int rl = w * 16 + i;
        int r = r0 + rl;
        int c_ = cnt[b * RR + r];                        // scalar broadcast
        float val = 0.0f;
        if (c_ > 0) {
            val = acc[((size_t)b * RR + r) * CC + lane] / (float)c_;
        }
        lt[rl][lane] = val;
    }
    __syncthreads();

    float* ob = out + (size_t)b * CC * RR;
#pragma unroll
    for (int it = 0; it < 16; ++it) {
        int idx = it * 256 + tid;
        int c = idx >> 6, rr = idx & 63;                 // c uniform per wave
        ob[(size_t)c * RR + r0 + rr] = lt[rr][c];        // 256B coalesced
    }
}

// ---------------- fallback (round-2 CSR path, ~5.9 MB ws) ----------------

__global__ void vox_index_fb(const float* __restrict__ coords,
                             int* __restrict__ hist,
                             int* __restrict__ vid,
                             int* __restrict__ rank) {
    int t = blockIdx.x * blockDim.x + threadIdx.x;
    int b = t >> 14;
    int v = voxel_id(coords, t);
    vid[t] = v;
    rank[t] = atomicAdd(&hist[b * SS + v], 1);
}

__global__ void vox_scan_fb(const int* __restrict__ hist,
                            int* __restrict__ offs) {
    __shared__ int part[256];
    int b = blockIdx.x;
    const int* h = hist + b * SS;
    int* o = offs + b * SS;
    int t = threadIdx.x;
    int base = t * RBLK;
    int end = min(base + RBLK, RR);
    int s = 0;
    for (int i = base; i < end; ++i) s += h[i];
    part[t] = s;
    __syncthreads();
    for (int d = 1; d < 256; d <<= 1) {
        int v = (t >= d) ? part[t - d] : 0;
        __syncthreads();
        part[t] += v;
        __syncthreads();
    }
    int run = (t == 0) ? 0 : part[t - 1];
    for (int i = base; i < end; ++i) {
        o[i] = run;
        run += h[i];
    }
    if (t == 255) o[RR] = part[255];
}

__global__ void vox_sort_fb(const int* __restrict__ vid,
                            const int* __restrict__ rank,
                            const int* __restrict__ offs,
                            int* __restrict__ sidx) {
    int t = blockIdx.x * blockDim.x + threadIdx.x;
    int b = t >> 14;
    int pos = offs[b * SS + vid[t]] + rank[t];
    sidx[b * NN + pos] = t & (NN - 1);
}

__global__ void vox_gather_fb(const float* __restrict__ feat,
                              const int* __restrict__ offs,
                              const int* __restrict__ sidx,
                              float* __restrict__ out) {
    int blk = blockIdx.x;
    int rb = blk % RBLK;
    int bc = blk / RBLK;
    int r = rb * 256 + threadIdx.x;
    if (r >= RR) return;
    int b = bc >> 6;
    const int* o = offs + b * SS;
    int start = o[r], end = o[r + 1];
    const int* si = sidx + b * NN;
    const float* f = feat + (size_t)bc * NN;
    float sum = 0.0f;
    for (int j = start; j < end; ++j) sum += f[si[j]];
    out[(size_t)bc * RR + r] = sum / (float)max(end - start, 1);
}

extern "C" void kernel_launch(void* const* d_in, const int* in_sizes, int n_in,
                              void* d_out, int out_size, void* d_ws, size_t ws_size,
                              hipStream_t stream) {
    const float* feat   = (const float*)d_in[0];   // [B, C, N]
    const float* coords = (const float*)d_in[1];   // [B, N, 3]
    float* out = (float*)d_out;                    // [B, C, X, Y, Z]

    size_t acc_elems = (size_t)BB * RR * CC;               // 22,413,312
    size_t cnt_elems = (size_t)BB * RR;                    // 350,208
    size_t need_main = (acc_elems + cnt_elems) * 4;        // ~91.1 MB
    int pts = BB * NN;                                     // 262144

    if (ws_size >= need_main) {
        float* acc = (float*)d_ws;                         // [B][R][C]
        int* cnt = (int*)(acc + acc_elems);                // [B][R]

        hipMemsetAsync(d_ws, 0, need_main, stream);        // acc + cnt
        vox_scatter_t<<<BB * (NN / 64), 256, 0, stream>>>(feat, coords, acc, cnt);
        vox_finish<<<BB * NTILES, 256, 0, stream>>>(acc, cnt, out);
    } else {
        int* hist = (int*)d_ws;
        int* offs = hist + BB * SS;
        int* vid  = offs + BB * SS;
        int* rank = vid + BB * NN;
        int* sidx = rank + BB * NN;

        hipMemsetAsync(hist, 0, (size_t)BB * SS * sizeof(int), stream);
        vox_index_fb<<<pts / 256, 256, 0, stream>>>(coords, hist, vid, rank);
        vox_scan_fb<<<BB, 256, 0, stream>>>(hist, offs);
        vox_sort_fb<<<pts / 256, 256, 0, stream>>>(vid, rank, offs, sidx);
        vox_gather_fb<<<BB * CC * RBLK, 256, 0, stream>>>(feat, offs, sidx, out);
    }
}